// Round 7
// baseline (1019.533 us; speedup 1.0000x reference)
//
#include <hip/hip_runtime.h>
#include <cstdint>
#include <cmath>

// TropicalHashGrid forward, R6 (3rd resubmit: rounds 4-6 lost to infra).
// R2: level-major dispatch -> gathers are L2-hits.
// R3: pair-packing cut lane-requests 268M -> 180M.
// R4: sc0 L1-bypass NEUTRAL.
// R5: fp16 repack (hashed quads + dense 2x2 xy-quads) CONFIRMED request-cost
//     model: 815 -> 605us, exactly proportional to request count.
//     Now ~2.2 cyc/lane-request incl. stores (170M requests).
// R6: discriminate request-RATE bound vs LATENCY/MLP bound:
//     2 points/thread at pinned occupancy (__launch_bounds__(256,8), VGPR<=64)
//     -> 2x outstanding gathers per wave. Register diet: H1 = H0 ^ dxm
//     (dxm = (ux^(ux+1))&M, 1 reg/pt), straddle loads fetch single dword.
//     Paired f32x4 store kills 16.8M store requests (~12%) under either model.

typedef float    f32x2 __attribute__((ext_vector_type(2)));
typedef float    f32x4 __attribute__((ext_vector_type(4)));
typedef uint32_t u32x2 __attribute__((ext_vector_type(2)));
typedef uint32_t u32x4 __attribute__((ext_vector_type(4)));
typedef _Float16 h16x2 __attribute__((ext_vector_type(2)));

#define NLEVELS 16
#define HASHMAP (1 << 19)
#define HMASK ((uint32_t)(HASHMAP - 1))
#define PRIME_Y 2654435761u
#define PRIME_Z 805459861u
#define F16SCALE 1024.0f
#define F16UNSCALE (1.0f / 1024.0f)

struct HGParams {
    float scale[NLEVELS];
    int   res[NLEVELS];
    int   dense[NLEVELS];
    int   dpk_off[NLEVELS];  // tier-B fp32 dense pair repack, f32x4 units, -1 none
    int   hq_off[NLEVELS];   // fp16 hashed table, u32x4 units, -1 none
    int   dq_off[NLEVELS];   // fp16 dense 2x2 quad table, u32x4 units, -1 none
};

__device__ __forceinline__ uint32_t sel4(u32x4 q, uint32_t k) {
    const uint32_t a = (k & 1u) ? q.y : q.x;
    const uint32_t b = (k & 1u) ? q.w : q.z;
    return (k & 2u) ? b : a;
}
__device__ __forceinline__ void unpack_h2(uint32_t w, float& lo, float& hi) {
    const h16x2 h = __builtin_bit_cast(h16x2, w);
    lo = (float)h.x; hi = (float)h.y;
}
__device__ __forceinline__ uint32_t pack_h2(float a, float b) {
    h16x2 h; h.x = (_Float16)a; h.y = (_Float16)b;
    return __builtin_bit_cast(uint32_t, h);
}

// ---- fp16 repack: hashed tables (identity layout, scaled x1024) ----
__global__ __launch_bounds__(256) void repack_hashed_f16(
    const f32x4* __restrict__ table2, uint32_t* __restrict__ hqw, HGParams p)
{
    const int l = blockIdx.y;
    if (p.hq_off[l] < 0) return;
    const f32x4* __restrict__ src = table2 + (size_t)l * (HASHMAP / 2);
    u32x2* __restrict__ dst = (u32x2*)(hqw + (size_t)p.hq_off[l] * 4);
    for (int k = blockIdx.x * 256 + threadIdx.x; k < HASHMAP / 2;
         k += gridDim.x * 256) {
        const f32x4 v = src[k];   // two entries
        u32x2 w;
        w.x = pack_h2(v.x * F16SCALE, v.y * F16SCALE);
        w.y = pack_h2(v.z * F16SCALE, v.w * F16SCALE);
        dst[k] = w;
    }
}

// ---- fp16 repack: dense 2x2 xy-quads, clamps baked in ----
__global__ __launch_bounds__(256) void repack_dense_f16(
    const f32x2* __restrict__ table, u32x4* __restrict__ dqt, HGParams p)
{
    const int l = blockIdx.y;
    if (p.dq_off[l] < 0) return;
    const int res = p.res[l];
    const int rm = res - 1;
    const int r2 = res * res;
    const int res3 = r2 * res;
    const f32x2* __restrict__ src = table + (size_t)l * HASHMAP;
    u32x4* __restrict__ dst = dqt + p.dq_off[l];
    for (int k = blockIdx.x * 256 + threadIdx.x; k < res3;
         k += gridDim.x * 256) {
        const int x = k % res;
        const int t = k / res;
        const int y = t % res;
        const int dx = (x < rm) ? 1 : 0;
        const int dy = (y < rm) ? res : 0;
        const f32x2 e00 = src[k];
        const f32x2 e10 = src[k + dx];
        const f32x2 e01 = src[k + dy];
        const f32x2 e11 = src[k + dx + dy];
        u32x4 w;
        w.x = pack_h2(e00.x * F16SCALE, e00.y * F16SCALE);
        w.y = pack_h2(e10.x * F16SCALE, e10.y * F16SCALE);
        w.z = pack_h2(e01.x * F16SCALE, e01.y * F16SCALE);
        w.w = pack_h2(e11.x * F16SCALE, e11.y * F16SCALE);
        dst[k] = w;
    }
}

// ---- tier-B fp32 dense pair repack (fallback) ----
__global__ __launch_bounds__(256) void repack_dense_k(
    const f32x2* __restrict__ table, f32x4* __restrict__ dpk, HGParams p)
{
    const int l = blockIdx.y;
    if (!p.dense[l] || p.dpk_off[l] < 0) return;
    const int res = p.res[l];
    const int res3 = res * res * res;
    const f32x2* __restrict__ src = table + (size_t)l * HASHMAP;
    f32x4* __restrict__ dst = dpk + p.dpk_off[l];
    for (int k = blockIdx.x * 256 + threadIdx.x; k < res3; k += gridDim.x * 256) {
        const f32x2 a = src[k];
        const f32x2 b = src[k + 1];
        f32x4 v; v.x = a.x; v.y = a.y; v.z = b.x; v.w = b.y;
        dst[k] = v;
    }
}

// Tier-B fp32 per-point fallback (dead in practice when tier-A ws fits).
__device__ __forceinline__ void point_fp32(
    const f32x2* __restrict__ tbl, const f32x4* __restrict__ dpkt,
    bool dense, int res,
    float rx, float ry, float rz, int ix, int iy, int iz,
    float& ox, float& oy)
{
    const float wx0 = 1.0f - rx, wx1 = rx;
    const float wy_[2] = {1.0f - ry, ry};
    const float wz_[2] = {1.0f - rz, rz};
    float ax = 0.0f, ay = 0.0f;
    if (dense) {
        const int rm = res - 1;
        const int x0 = min(ix, rm), x1 = min(ix + 1, rm);
        const int y0 = min(iy, rm), y1 = min(iy + 1, rm);
        const int z0 = min(iz, rm), z1 = min(iz + 1, rm);
        const int r2 = res * res;
        const int ys[2] = {y0 * res, y1 * res};
        const int zs[2] = {z0 * r2,  z1 * r2};
        const int d = x1 - x0;
        if (dpkt) {
            f32x4 f4[4];
#pragma unroll
            for (int c = 0; c < 4; ++c)
                f4[c] = dpkt[x0 + ys[(c >> 1) & 1] + zs[c & 1]];
#pragma unroll
            for (int c = 0; c < 4; ++c) {
                const f32x2 c0 = f4[c].xy;
                const f32x2 c1 = d ? f4[c].zw : f4[c].xy;
                const float wyz = wy_[(c >> 1) & 1] * wz_[c & 1];
                ax += wyz * (wx0 * c0.x + wx1 * c1.x);
                ay += wyz * (wx0 * c0.y + wx1 * c1.y);
            }
        } else {
            f32x2 f0[4], f1[4];
#pragma unroll
            for (int c = 0; c < 4; ++c) {
                const int b = ys[(c >> 1) & 1] + zs[c & 1];
                f0[c] = tbl[x0 + b];
                f1[c] = tbl[x1 + b];
            }
#pragma unroll
            for (int c = 0; c < 4; ++c) {
                const float wyz = wy_[(c >> 1) & 1] * wz_[c & 1];
                ax += wyz * (wx0 * f0[c].x + wx1 * f1[c].x);
                ay += wyz * (wx0 * f0[c].y + wx1 * f1[c].y);
            }
        }
    } else {
        const uint32_t ux = (uint32_t)ix;
        const uint32_t hy[2] = {(uint32_t)iy * PRIME_Y, (uint32_t)(iy + 1) * PRIME_Y};
        const uint32_t hz[2] = {(uint32_t)iz * PRIME_Z, (uint32_t)(iz + 1) * PRIME_Z};
        uint32_t H0[4], H1[4];
#pragma unroll
        for (int c = 0; c < 4; ++c) {
            const uint32_t hyz = hy[(c >> 1) & 1] ^ hz[c & 1];
            H0[c] = (ux ^ hyz) & HMASK;
            H1[c] = ((ux + 1u) ^ hyz) & HMASK;
        }
        const f32x4* __restrict__ t4 = (const f32x4*)tbl;
        f32x4 f4[4];
#pragma unroll
        for (int c = 0; c < 4; ++c) f4[c] = t4[H0[c] >> 1];
        f32x2 c1v[4];
        if (ux & 1u) {
#pragma unroll
            for (int c = 0; c < 4; ++c) c1v[c] = tbl[H1[c]];
        } else {
#pragma unroll
            for (int c = 0; c < 4; ++c)
                c1v[c] = (H0[c] & 1u) ? f4[c].xy : f4[c].zw;
        }
#pragma unroll
        for (int c = 0; c < 4; ++c) {
            const f32x2 c0 = (H0[c] & 1u) ? f4[c].zw : f4[c].xy;
            const float wyz = wy_[(c >> 1) & 1] * wz_[c & 1];
            ax += wyz * (wx0 * c0.x + wx1 * c1v[c].x);
            ay += wyz * (wx0 * c0.y + wx1 * c1v[c].y);
        }
    }
    ox = ax; oy = ay;
}

// One block = 512 points x 1 level (2 points/thread for doubled MLP).
// Level = blockIdx.y (slowest dim -> one level's table hot per XCD L2).
__global__ __launch_bounds__(256, 8) void hashgrid_level(
    const float* __restrict__ x,
    const float* __restrict__ table,
    const f32x4* __restrict__ dpk,   // tier-B fp32 dense pairs or nullptr
    const u32x4* __restrict__ hq,    // fp16 hashed tables or nullptr
    const u32x4* __restrict__ dq,    // fp16 dense quads or nullptr
    f32x2* __restrict__ dst,
    HGParams p,
    int npoints,
    size_t stride_l,
    size_t stride_n)
{
    __shared__ float sx[1536];
    const int tid = threadIdx.x;
    const int base = blockIdx.x << 9;   // 512 points/block
    const int l = blockIdx.y;

    const int total = npoints * 3;
    const int sbase = base * 3;
#pragma unroll
    for (int k = 0; k < 6; ++k) {
        const int li = tid + (k << 8);
        const int gi = sbase + li;
        sx[li] = (gi < total) ? x[gi] : 0.0f;
    }
    __syncthreads();

    const int n0 = base + (tid << 1);
    if (n0 >= npoints) return;
    const bool pair = (n0 + 1) < npoints;

    const float scale = p.scale[l];
    const int   res   = p.res[l];
    const bool  dense = (p.dense[l] != 0);

    float rx[2], ry[2], rz[2];
    int ixv[2], iyv[2], izv[2];
#pragma unroll
    for (int j = 0; j < 2; ++j) {
        const int s = ((tid << 1) | j) * 3;
        const float px = sx[s + 0] * scale + 0.5f;
        const float py = sx[s + 1] * scale + 0.5f;
        const float pz = sx[s + 2] * scale + 0.5f;
        const float fx = floorf(px), fy = floorf(py), fz = floorf(pz);
        rx[j] = px - fx; ry[j] = py - fy; rz[j] = pz - fz;
        ixv[j] = (int)fx; iyv[j] = (int)fy; izv[j] = (int)fz;
    }

    float ox[2], oy[2];

    if (dense && dq && p.dq_off[l] >= 0) {
        // fp16 2x2 xy-quads: one 16B request per z-corner, 2 pts interleaved.
        const u32x4* __restrict__ dt = dq + p.dq_off[l];
        const int rm = res - 1, r2 = res * res;
        u32x4 qa[2], qb[2];
#pragma unroll
        for (int j = 0; j < 2; ++j) {
            const int x0 = min(ixv[j], rm), y0 = min(iyv[j], rm);
            const int z0 = min(izv[j], rm), z1 = min(izv[j] + 1, rm);
            const int b = x0 + y0 * res;
            qa[j] = dt[b + z0 * r2];
            qb[j] = dt[b + z1 * r2];
        }
#pragma unroll
        for (int j = 0; j < 2; ++j) {
            const float wx0 = 1.0f - rx[j], wx1 = rx[j];
            const float wy0 = 1.0f - ry[j], wy1 = ry[j];
            const float wz0 = 1.0f - rz[j], wz1 = rz[j];
            float a00x, a00y, a10x, a10y, a01x, a01y, a11x, a11y;
            unpack_h2(qa[j].x, a00x, a00y);
            unpack_h2(qa[j].y, a10x, a10y);
            unpack_h2(qa[j].z, a01x, a01y);
            unpack_h2(qa[j].w, a11x, a11y);
            const float bax = wy0 * (wx0 * a00x + wx1 * a10x)
                            + wy1 * (wx0 * a01x + wx1 * a11x);
            const float bay = wy0 * (wx0 * a00y + wx1 * a10y)
                            + wy1 * (wx0 * a01y + wx1 * a11y);
            float b00x, b00y, b10x, b10y, b01x, b01y, b11x, b11y;
            unpack_h2(qb[j].x, b00x, b00y);
            unpack_h2(qb[j].y, b10x, b10y);
            unpack_h2(qb[j].z, b01x, b01y);
            unpack_h2(qb[j].w, b11x, b11y);
            const float bbx = wy0 * (wx0 * b00x + wx1 * b10x)
                            + wy1 * (wx0 * b01x + wx1 * b11x);
            const float bby = wy0 * (wx0 * b00y + wx1 * b10y)
                            + wy1 * (wx0 * b01y + wx1 * b11y);
            ox[j] = (wz0 * bax + wz1 * bbx) * F16UNSCALE;
            oy[j] = (wz0 * bay + wz1 * bby) * F16UNSCALE;
        }
    } else if (!dense && hq && p.hq_off[l] >= 0) {
        // fp16 hashed quads, 2 points: 8 quad loads + masked straddle dwords.
        const u32x4* __restrict__ ht = hq + p.hq_off[l];
        const uint32_t* __restrict__ htw = (const uint32_t*)ht;
        uint32_t H0[2][4], dxm[2];
        bool st[2];
#pragma unroll
        for (int j = 0; j < 2; ++j) {
            const uint32_t ux = (uint32_t)ixv[j];
            const uint32_t hy0 = (uint32_t)iyv[j] * PRIME_Y;
            const uint32_t hy1 = (uint32_t)(iyv[j] + 1) * PRIME_Y;
            const uint32_t hz0 = (uint32_t)izv[j] * PRIME_Z;
            const uint32_t hz1 = (uint32_t)(izv[j] + 1) * PRIME_Z;
#pragma unroll
            for (int c = 0; c < 4; ++c) {
                const uint32_t hyz = ((c & 2) ? hy1 : hy0) ^ ((c & 1) ? hz1 : hz0);
                H0[j][c] = (ux ^ hyz) & HMASK;
            }
            dxm[j] = (ux ^ (ux + 1u)) & HMASK;  // H1 = H0 ^ dxm
            st[j] = (dxm[j] >= 4u);             // quad-straddle iff ix%4==3
        }
        u32x4 q0[2][4];
#pragma unroll
        for (int j = 0; j < 2; ++j)
#pragma unroll
            for (int c = 0; c < 4; ++c)
                q0[j][c] = ht[H0[j][c] >> 2];
        uint32_t sE[2][4];
#pragma unroll
        for (int j = 0; j < 2; ++j) {
            if (st[j]) {
#pragma unroll
                for (int c = 0; c < 4; ++c)
                    sE[j][c] = htw[H0[j][c] ^ dxm[j]];  // single-dword fetch
            }
        }
#pragma unroll
        for (int j = 0; j < 2; ++j) {
            const float wx0 = 1.0f - rx[j], wx1 = rx[j];
            const float wy0 = 1.0f - ry[j], wy1 = ry[j];
            const float wz0 = 1.0f - rz[j], wz1 = rz[j];
            float ax = 0.0f, ay = 0.0f;
#pragma unroll
            for (int c = 0; c < 4; ++c) {
                const uint32_t k0 = H0[j][c] & 3u;
                const uint32_t e0 = sel4(q0[j][c], k0);
                const uint32_t e1 = st[j] ? sE[j][c]
                                          : sel4(q0[j][c], k0 ^ (dxm[j] & 3u));
                float c0x, c0y, c1x, c1y;
                unpack_h2(e0, c0x, c0y);
                unpack_h2(e1, c1x, c1y);
                const float wyz = ((c & 2) ? wy1 : wy0) * ((c & 1) ? wz1 : wz0);
                ax += wyz * (wx0 * c0x + wx1 * c1x);
                ay += wyz * (wx0 * c0y + wx1 * c1y);
            }
            ox[j] = ax * F16UNSCALE;
            oy[j] = ay * F16UNSCALE;
        }
    } else {
        // tier-B fp32 fallback, sequential per point.
        const f32x2* __restrict__ tbl =
            (const f32x2*)table + (size_t)l * (size_t)HASHMAP;
        const f32x4* __restrict__ dpkt =
            (dense && dpk && p.dpk_off[l] >= 0) ? (dpk + p.dpk_off[l]) : nullptr;
#pragma unroll
        for (int j = 0; j < 2; ++j)
            point_fp32(tbl, dpkt, dense, res,
                       rx[j], ry[j], rz[j], ixv[j], iyv[j], izv[j],
                       ox[j], oy[j]);
    }

    const size_t db = (size_t)l * stride_l;
    if (pair && stride_n == 1) {
        // n0 even, npoints even on ws path -> 16B-aligned paired store.
        f32x4 v; v.x = ox[0]; v.y = oy[0]; v.z = ox[1]; v.w = oy[1];
        __builtin_nontemporal_store(v, (f32x4*)(dst + db + (size_t)n0));
    } else {
        f32x2 a; a.x = ox[0]; a.y = oy[0];
        __builtin_nontemporal_store(a, dst + db + (size_t)n0 * stride_n);
        if (pair) {
            f32x2 b2; b2.x = ox[1]; b2.y = oy[1];
            __builtin_nontemporal_store(b2, dst + db + (size_t)(n0 + 1) * stride_n);
        }
    }
}

// Transpose [16][N] f32x2 -> [N][16] f32x2, float4 on both global sides.
__global__ __launch_bounds__(256) void transpose_out(
    const f32x4* __restrict__ ws4,
    f32x4* __restrict__ out4,
    int npoints)
{
    __shared__ f32x2 tile[NLEVELS][130];
    const int tid = threadIdx.x;
    const int base = blockIdx.x << 7;    // 128 points per block
    const int np2 = npoints >> 1;

#pragma unroll
    for (int k = 0; k < 4; ++k) {
        const int flat = tid + (k << 8);
        const int l  = flat >> 6;
        const int pr = flat & 63;
        const int gp = (base >> 1) + pr;
        if (gp < np2) {
            const f32x4 v = __builtin_nontemporal_load(ws4 + (size_t)l * np2 + gp);
            tile[l][2 * pr]     = v.xy;
            tile[l][2 * pr + 1] = v.zw;
        }
    }
    __syncthreads();

#pragma unroll
    for (int k = 0; k < 4; ++k) {
        const int flat = tid + (k << 8);
        const int nl = flat >> 3;
        const int c  = flat & 7;
        const int nn = base + nl;
        if (nn < npoints) {
            const f32x2 a = tile[2 * c][nl];
            const f32x2 b = tile[2 * c + 1][nl];
            f32x4 v; v.x = a.x; v.y = a.y; v.z = b.x; v.w = b.y;
            __builtin_nontemporal_store(v, out4 + (size_t)nn * 8 + c);
        }
    }
}

extern "C" void kernel_launch(void* const* d_in, const int* in_sizes, int n_in,
                              void* d_out, int out_size, void* d_ws, size_t ws_size,
                              hipStream_t stream) {
    const float* x     = (const float*)d_in[0];
    const float* table = (const float*)d_in[1];
    float* out         = (float*)d_out;
    const int npoints  = in_sizes[0] / 3;

    HGParams p;
    const double B = pow(2.0, 7.0 / 15.0);
    int dpk_total = 0;   // f32x4 entries for tier-B dense repack
    int dq_total = 0;    // u32x4 entries for fp16 dense quads
    int hq_total = 0;    // u32x4 entries for fp16 hashed tables
    int max_res3 = 0;
    for (int l = 0; l < NLEVELS; ++l) {
        const double s = 16.0 * pow(B, (double)l) - 1.0;
        p.scale[l] = (float)s;
        const int res = (int)ceil(s) + 1;
        p.res[l] = res;
        const long long r3 = (long long)res * res * res;
        p.dense[l] = (r3 <= (long long)HASHMAP) ? 1 : 0;
        if (p.dense[l]) {
            p.dpk_off[l] = dpk_total;  dpk_total += (int)r3;
            p.dq_off[l]  = dq_total;   dq_total  += (int)r3;
            p.hq_off[l]  = -1;
            if ((int)r3 > max_res3) max_res3 = (int)r3;
        } else {
            p.dpk_off[l] = -1;
            p.dq_off[l]  = -1;
            p.hq_off[l]  = hq_total;   hq_total  += HASHMAP / 4;
        }
    }

    const size_t need_main = (size_t)npoints * NLEVELS * sizeof(f32x2);
    const bool ws_main = (ws_size >= need_main) && ((npoints & 1) == 0);
    const size_t off0 = ws_main ? need_main : 0;

    const size_t hq_bytes = (size_t)hq_total * 16;
    const size_t dq_bytes = (size_t)dq_total * 16;
    const bool tierA = (ws_size >= off0 + hq_bytes + dq_bytes);

    const u32x4* hq = nullptr;
    const u32x4* dq = nullptr;
    const f32x4* dpk = nullptr;

    if (tierA) {
        uint32_t* hqw = (uint32_t*)((char*)d_ws + off0);
        u32x4*    dqt = (u32x4*)((char*)d_ws + off0 + hq_bytes);
        hq = (const u32x4*)hqw;
        dq = dqt;
        {
            const dim3 gr(1024, NLEVELS);
            repack_hashed_f16<<<gr, 256, 0, stream>>>(
                (const f32x4*)table, hqw, p);
        }
        {
            const dim3 gr((max_res3 + 255) / 256, NLEVELS);
            repack_dense_f16<<<gr, 256, 0, stream>>>(
                (const f32x2*)table, dqt, p);
        }
    } else {
        // tier B: fp32 dense pair repack only
        for (int l = 0; l < NLEVELS; ++l) { p.hq_off[l] = -1; p.dq_off[l] = -1; }
        const size_t need_dpk = (size_t)dpk_total * sizeof(f32x4);
        const bool use_dpk = (ws_size >= off0 + need_dpk) && dpk_total > 0;
        if (use_dpk) {
            f32x4* dpkw = (f32x4*)((char*)d_ws + off0);
            dpk = dpkw;
            const dim3 gr((max_res3 + 255) / 256, NLEVELS);
            repack_dense_k<<<gr, 256, 0, stream>>>((const f32x2*)table, dpkw, p);
        } else {
            for (int l = 0; l < NLEVELS; ++l) p.dpk_off[l] = -1;
        }
    }

    const dim3 g1((npoints + 511) / 512, NLEVELS);
    if (ws_main) {
        hashgrid_level<<<g1, 256, 0, stream>>>(
            x, table, dpk, hq, dq, (f32x2*)d_ws, p, npoints,
            (size_t)npoints, (size_t)1);
        const int nb2 = (npoints + 127) / 128;
        transpose_out<<<nb2, 256, 0, stream>>>(
            (const f32x4*)d_ws, (f32x4*)out, npoints);
    } else {
        hashgrid_level<<<g1, 256, 0, stream>>>(
            x, table, dpk, hq, dq, (f32x2*)out, p, npoints,
            (size_t)1, (size_t)NLEVELS);
    }
}

// Round 8
// 932.956 us; speedup vs baseline: 1.0928x; 1.0928x over previous
//
#include <hip/hip_runtime.h>
#include <cstdint>
#include <cmath>

// TropicalHashGrid forward, R7.
// R2: level-major dispatch -> gathers are L2-hits.
// R3: pair-packing cut lane-requests 268M -> 180M.
// R4: sc0 L1-bypass NEUTRAL.
// R5: fp16 repack CONFIRMED request-cost model: 815 -> 605us (prop. to count).
// R6: 2pt/thread @ __launch_bounds__(256,8): CONFOUNDED by spills
//     (64-VGPR cap too tight: WRITE_SIZE 262->948MB, dur 605->680).
// R7: same MLP experiment, spill-free: __launch_bounds__(256,6) = 85-VGPR cap,
//     24 waves/CU (75% occ). Outstanding gathers/CU ~216 vs R5's ~130.
//     Discriminates latency/MLP-bound (~430-470us) vs request-rate-bound
//     (~560-605us). Tripwire: WRITE_SIZE must be ~262144 KB (no scratch).

typedef float    f32x2 __attribute__((ext_vector_type(2)));
typedef float    f32x4 __attribute__((ext_vector_type(4)));
typedef uint32_t u32x2 __attribute__((ext_vector_type(2)));
typedef uint32_t u32x4 __attribute__((ext_vector_type(4)));
typedef _Float16 h16x2 __attribute__((ext_vector_type(2)));

#define NLEVELS 16
#define HASHMAP (1 << 19)
#define HMASK ((uint32_t)(HASHMAP - 1))
#define PRIME_Y 2654435761u
#define PRIME_Z 805459861u
#define F16SCALE 1024.0f
#define F16UNSCALE (1.0f / 1024.0f)

struct HGParams {
    float scale[NLEVELS];
    int   res[NLEVELS];
    int   dense[NLEVELS];
    int   dpk_off[NLEVELS];  // tier-B fp32 dense pair repack, f32x4 units, -1 none
    int   hq_off[NLEVELS];   // fp16 hashed table, u32x4 units, -1 none
    int   dq_off[NLEVELS];   // fp16 dense 2x2 quad table, u32x4 units, -1 none
};

__device__ __forceinline__ uint32_t sel4(u32x4 q, uint32_t k) {
    const uint32_t a = (k & 1u) ? q.y : q.x;
    const uint32_t b = (k & 1u) ? q.w : q.z;
    return (k & 2u) ? b : a;
}
__device__ __forceinline__ void unpack_h2(uint32_t w, float& lo, float& hi) {
    const h16x2 h = __builtin_bit_cast(h16x2, w);
    lo = (float)h.x; hi = (float)h.y;
}
__device__ __forceinline__ uint32_t pack_h2(float a, float b) {
    h16x2 h; h.x = (_Float16)a; h.y = (_Float16)b;
    return __builtin_bit_cast(uint32_t, h);
}

// ---- fp16 repack: hashed tables (identity layout, scaled x1024) ----
__global__ __launch_bounds__(256) void repack_hashed_f16(
    const f32x4* __restrict__ table2, uint32_t* __restrict__ hqw, HGParams p)
{
    const int l = blockIdx.y;
    if (p.hq_off[l] < 0) return;
    const f32x4* __restrict__ src = table2 + (size_t)l * (HASHMAP / 2);
    u32x2* __restrict__ dst = (u32x2*)(hqw + (size_t)p.hq_off[l] * 4);
    for (int k = blockIdx.x * 256 + threadIdx.x; k < HASHMAP / 2;
         k += gridDim.x * 256) {
        const f32x4 v = src[k];   // two entries
        u32x2 w;
        w.x = pack_h2(v.x * F16SCALE, v.y * F16SCALE);
        w.y = pack_h2(v.z * F16SCALE, v.w * F16SCALE);
        dst[k] = w;
    }
}

// ---- fp16 repack: dense 2x2 xy-quads, clamps baked in ----
__global__ __launch_bounds__(256) void repack_dense_f16(
    const f32x2* __restrict__ table, u32x4* __restrict__ dqt, HGParams p)
{
    const int l = blockIdx.y;
    if (p.dq_off[l] < 0) return;
    const int res = p.res[l];
    const int rm = res - 1;
    const int r2 = res * res;
    const int res3 = r2 * res;
    const f32x2* __restrict__ src = table + (size_t)l * HASHMAP;
    u32x4* __restrict__ dst = dqt + p.dq_off[l];
    for (int k = blockIdx.x * 256 + threadIdx.x; k < res3;
         k += gridDim.x * 256) {
        const int x = k % res;
        const int t = k / res;
        const int y = t % res;
        const int dx = (x < rm) ? 1 : 0;
        const int dy = (y < rm) ? res : 0;
        const f32x2 e00 = src[k];
        const f32x2 e10 = src[k + dx];
        const f32x2 e01 = src[k + dy];
        const f32x2 e11 = src[k + dx + dy];
        u32x4 w;
        w.x = pack_h2(e00.x * F16SCALE, e00.y * F16SCALE);
        w.y = pack_h2(e10.x * F16SCALE, e10.y * F16SCALE);
        w.z = pack_h2(e01.x * F16SCALE, e01.y * F16SCALE);
        w.w = pack_h2(e11.x * F16SCALE, e11.y * F16SCALE);
        dst[k] = w;
    }
}

// ---- tier-B fp32 dense pair repack (fallback) ----
__global__ __launch_bounds__(256) void repack_dense_k(
    const f32x2* __restrict__ table, f32x4* __restrict__ dpk, HGParams p)
{
    const int l = blockIdx.y;
    if (!p.dense[l] || p.dpk_off[l] < 0) return;
    const int res = p.res[l];
    const int res3 = res * res * res;
    const f32x2* __restrict__ src = table + (size_t)l * HASHMAP;
    f32x4* __restrict__ dst = dpk + p.dpk_off[l];
    for (int k = blockIdx.x * 256 + threadIdx.x; k < res3; k += gridDim.x * 256) {
        const f32x2 a = src[k];
        const f32x2 b = src[k + 1];
        f32x4 v; v.x = a.x; v.y = a.y; v.z = b.x; v.w = b.y;
        dst[k] = v;
    }
}

// Tier-B fp32 per-point fallback (dead in practice when tier-A ws fits).
__device__ __forceinline__ void point_fp32(
    const f32x2* __restrict__ tbl, const f32x4* __restrict__ dpkt,
    bool dense, int res,
    float rx, float ry, float rz, int ix, int iy, int iz,
    float& ox, float& oy)
{
    const float wx0 = 1.0f - rx, wx1 = rx;
    const float wy_[2] = {1.0f - ry, ry};
    const float wz_[2] = {1.0f - rz, rz};
    float ax = 0.0f, ay = 0.0f;
    if (dense) {
        const int rm = res - 1;
        const int x0 = min(ix, rm), x1 = min(ix + 1, rm);
        const int y0 = min(iy, rm), y1 = min(iy + 1, rm);
        const int z0 = min(iz, rm), z1 = min(iz + 1, rm);
        const int r2 = res * res;
        const int ys[2] = {y0 * res, y1 * res};
        const int zs[2] = {z0 * r2,  z1 * r2};
        const int d = x1 - x0;
        if (dpkt) {
            f32x4 f4[4];
#pragma unroll
            for (int c = 0; c < 4; ++c)
                f4[c] = dpkt[x0 + ys[(c >> 1) & 1] + zs[c & 1]];
#pragma unroll
            for (int c = 0; c < 4; ++c) {
                const f32x2 c0 = f4[c].xy;
                const f32x2 c1 = d ? f4[c].zw : f4[c].xy;
                const float wyz = wy_[(c >> 1) & 1] * wz_[c & 1];
                ax += wyz * (wx0 * c0.x + wx1 * c1.x);
                ay += wyz * (wx0 * c0.y + wx1 * c1.y);
            }
        } else {
            f32x2 f0[4], f1[4];
#pragma unroll
            for (int c = 0; c < 4; ++c) {
                const int b = ys[(c >> 1) & 1] + zs[c & 1];
                f0[c] = tbl[x0 + b];
                f1[c] = tbl[x1 + b];
            }
#pragma unroll
            for (int c = 0; c < 4; ++c) {
                const float wyz = wy_[(c >> 1) & 1] * wz_[c & 1];
                ax += wyz * (wx0 * f0[c].x + wx1 * f1[c].x);
                ay += wyz * (wx0 * f0[c].y + wx1 * f1[c].y);
            }
        }
    } else {
        const uint32_t ux = (uint32_t)ix;
        const uint32_t hy[2] = {(uint32_t)iy * PRIME_Y, (uint32_t)(iy + 1) * PRIME_Y};
        const uint32_t hz[2] = {(uint32_t)iz * PRIME_Z, (uint32_t)(iz + 1) * PRIME_Z};
        uint32_t H0[4], H1[4];
#pragma unroll
        for (int c = 0; c < 4; ++c) {
            const uint32_t hyz = hy[(c >> 1) & 1] ^ hz[c & 1];
            H0[c] = (ux ^ hyz) & HMASK;
            H1[c] = ((ux + 1u) ^ hyz) & HMASK;
        }
        const f32x4* __restrict__ t4 = (const f32x4*)tbl;
        f32x4 f4[4];
#pragma unroll
        for (int c = 0; c < 4; ++c) f4[c] = t4[H0[c] >> 1];
        f32x2 c1v[4];
        if (ux & 1u) {
#pragma unroll
            for (int c = 0; c < 4; ++c) c1v[c] = tbl[H1[c]];
        } else {
#pragma unroll
            for (int c = 0; c < 4; ++c)
                c1v[c] = (H0[c] & 1u) ? f4[c].xy : f4[c].zw;
        }
#pragma unroll
        for (int c = 0; c < 4; ++c) {
            const f32x2 c0 = (H0[c] & 1u) ? f4[c].zw : f4[c].xy;
            const float wyz = wy_[(c >> 1) & 1] * wz_[c & 1];
            ax += wyz * (wx0 * c0.x + wx1 * c1v[c].x);
            ay += wyz * (wx0 * c0.y + wx1 * c1v[c].y);
        }
    }
    ox = ax; oy = ay;
}

// One block = 512 points x 1 level (2 points/thread for doubled MLP).
// Level = blockIdx.y (slowest dim -> one level's table hot per XCD L2).
// __launch_bounds__(256,6): 85-VGPR cap -- enough for the ~80-reg 2pt hashed
// path (R6's 64-reg cap spilled), still 75% occupancy.
__global__ __launch_bounds__(256, 6) void hashgrid_level(
    const float* __restrict__ x,
    const float* __restrict__ table,
    const f32x4* __restrict__ dpk,   // tier-B fp32 dense pairs or nullptr
    const u32x4* __restrict__ hq,    // fp16 hashed tables or nullptr
    const u32x4* __restrict__ dq,    // fp16 dense quads or nullptr
    f32x2* __restrict__ dst,
    HGParams p,
    int npoints,
    size_t stride_l,
    size_t stride_n)
{
    __shared__ float sx[1536];
    const int tid = threadIdx.x;
    const int base = blockIdx.x << 9;   // 512 points/block
    const int l = blockIdx.y;

    const int total = npoints * 3;
    const int sbase = base * 3;
#pragma unroll
    for (int k = 0; k < 6; ++k) {
        const int li = tid + (k << 8);
        const int gi = sbase + li;
        sx[li] = (gi < total) ? x[gi] : 0.0f;
    }
    __syncthreads();

    const int n0 = base + (tid << 1);
    if (n0 >= npoints) return;
    const bool pair = (n0 + 1) < npoints;

    const float scale = p.scale[l];
    const int   res   = p.res[l];
    const bool  dense = (p.dense[l] != 0);

    float rx[2], ry[2], rz[2];
    int ixv[2], iyv[2], izv[2];
#pragma unroll
    for (int j = 0; j < 2; ++j) {
        const int s = ((tid << 1) | j) * 3;
        const float px = sx[s + 0] * scale + 0.5f;
        const float py = sx[s + 1] * scale + 0.5f;
        const float pz = sx[s + 2] * scale + 0.5f;
        const float fx = floorf(px), fy = floorf(py), fz = floorf(pz);
        rx[j] = px - fx; ry[j] = py - fy; rz[j] = pz - fz;
        ixv[j] = (int)fx; iyv[j] = (int)fy; izv[j] = (int)fz;
    }

    float ox[2], oy[2];

    if (dense && dq && p.dq_off[l] >= 0) {
        // fp16 2x2 xy-quads: one 16B request per z-corner, 2 pts interleaved.
        const u32x4* __restrict__ dt = dq + p.dq_off[l];
        const int rm = res - 1, r2 = res * res;
        u32x4 qa[2], qb[2];
#pragma unroll
        for (int j = 0; j < 2; ++j) {
            const int x0 = min(ixv[j], rm), y0 = min(iyv[j], rm);
            const int z0 = min(izv[j], rm), z1 = min(izv[j] + 1, rm);
            const int b = x0 + y0 * res;
            qa[j] = dt[b + z0 * r2];
            qb[j] = dt[b + z1 * r2];
        }
#pragma unroll
        for (int j = 0; j < 2; ++j) {
            const float wx0 = 1.0f - rx[j], wx1 = rx[j];
            const float wy0 = 1.0f - ry[j], wy1 = ry[j];
            const float wz0 = 1.0f - rz[j], wz1 = rz[j];
            float a00x, a00y, a10x, a10y, a01x, a01y, a11x, a11y;
            unpack_h2(qa[j].x, a00x, a00y);
            unpack_h2(qa[j].y, a10x, a10y);
            unpack_h2(qa[j].z, a01x, a01y);
            unpack_h2(qa[j].w, a11x, a11y);
            const float bax = wy0 * (wx0 * a00x + wx1 * a10x)
                            + wy1 * (wx0 * a01x + wx1 * a11x);
            const float bay = wy0 * (wx0 * a00y + wx1 * a10y)
                            + wy1 * (wx0 * a01y + wx1 * a11y);
            float b00x, b00y, b10x, b10y, b01x, b01y, b11x, b11y;
            unpack_h2(qb[j].x, b00x, b00y);
            unpack_h2(qb[j].y, b10x, b10y);
            unpack_h2(qb[j].z, b01x, b01y);
            unpack_h2(qb[j].w, b11x, b11y);
            const float bbx = wy0 * (wx0 * b00x + wx1 * b10x)
                            + wy1 * (wx0 * b01x + wx1 * b11x);
            const float bby = wy0 * (wx0 * b00y + wx1 * b10y)
                            + wy1 * (wx0 * b01y + wx1 * b11y);
            ox[j] = (wz0 * bax + wz1 * bbx) * F16UNSCALE;
            oy[j] = (wz0 * bay + wz1 * bby) * F16UNSCALE;
        }
    } else if (!dense && hq && p.hq_off[l] >= 0) {
        // fp16 hashed quads, 2 points: 8 quad loads + masked straddle dwords.
        const u32x4* __restrict__ ht = hq + p.hq_off[l];
        const uint32_t* __restrict__ htw = (const uint32_t*)ht;
        uint32_t H0[2][4], dxm[2];
#pragma unroll
        for (int j = 0; j < 2; ++j) {
            const uint32_t ux = (uint32_t)ixv[j];
            const uint32_t hy0 = (uint32_t)iyv[j] * PRIME_Y;
            const uint32_t hy1 = (uint32_t)(iyv[j] + 1) * PRIME_Y;
            const uint32_t hz0 = (uint32_t)izv[j] * PRIME_Z;
            const uint32_t hz1 = (uint32_t)(izv[j] + 1) * PRIME_Z;
#pragma unroll
            for (int c = 0; c < 4; ++c) {
                const uint32_t hyz = ((c & 2) ? hy1 : hy0) ^ ((c & 1) ? hz1 : hz0);
                H0[j][c] = (ux ^ hyz) & HMASK;
            }
            dxm[j] = (ux ^ (ux + 1u)) & HMASK;  // H1 = H0 ^ dxm
        }
        u32x4 q0[2][4];
#pragma unroll
        for (int j = 0; j < 2; ++j)
#pragma unroll
            for (int c = 0; c < 4; ++c)
                q0[j][c] = ht[H0[j][c] >> 2];
        uint32_t sE[2][4];
#pragma unroll
        for (int j = 0; j < 2; ++j) {
            if (dxm[j] >= 4u) {                 // quad-straddle iff ix%4==3
#pragma unroll
                for (int c = 0; c < 4; ++c)
                    sE[j][c] = htw[H0[j][c] ^ dxm[j]];  // single-dword fetch
            }
        }
#pragma unroll
        for (int j = 0; j < 2; ++j) {
            const float wx0 = 1.0f - rx[j], wx1 = rx[j];
            const float wy0 = 1.0f - ry[j], wy1 = ry[j];
            const float wz0 = 1.0f - rz[j], wz1 = rz[j];
            const bool st = (dxm[j] >= 4u);
            float ax = 0.0f, ay = 0.0f;
#pragma unroll
            for (int c = 0; c < 4; ++c) {
                const uint32_t k0 = H0[j][c] & 3u;
                const uint32_t e0 = sel4(q0[j][c], k0);
                const uint32_t e1 = st ? sE[j][c]
                                       : sel4(q0[j][c], k0 ^ (dxm[j] & 3u));
                float c0x, c0y, c1x, c1y;
                unpack_h2(e0, c0x, c0y);
                unpack_h2(e1, c1x, c1y);
                const float wyz = ((c & 2) ? wy1 : wy0) * ((c & 1) ? wz1 : wz0);
                ax += wyz * (wx0 * c0x + wx1 * c1x);
                ay += wyz * (wx0 * c0y + wx1 * c1y);
            }
            ox[j] = ax * F16UNSCALE;
            oy[j] = ay * F16UNSCALE;
        }
    } else {
        // tier-B fp32 fallback, sequential per point.
        const f32x2* __restrict__ tbl =
            (const f32x2*)table + (size_t)l * (size_t)HASHMAP;
        const f32x4* __restrict__ dpkt =
            (dense && dpk && p.dpk_off[l] >= 0) ? (dpk + p.dpk_off[l]) : nullptr;
#pragma unroll
        for (int j = 0; j < 2; ++j)
            point_fp32(tbl, dpkt, dense, res,
                       rx[j], ry[j], rz[j], ixv[j], iyv[j], izv[j],
                       ox[j], oy[j]);
    }

    const size_t db = (size_t)l * stride_l;
    if (pair && stride_n == 1) {
        // n0 even, npoints even on ws path -> 16B-aligned paired store.
        f32x4 v; v.x = ox[0]; v.y = oy[0]; v.z = ox[1]; v.w = oy[1];
        __builtin_nontemporal_store(v, (f32x4*)(dst + db + (size_t)n0));
    } else {
        f32x2 a; a.x = ox[0]; a.y = oy[0];
        __builtin_nontemporal_store(a, dst + db + (size_t)n0 * stride_n);
        if (pair) {
            f32x2 b2; b2.x = ox[1]; b2.y = oy[1];
            __builtin_nontemporal_store(b2, dst + db + (size_t)(n0 + 1) * stride_n);
        }
    }
}

// Transpose [16][N] f32x2 -> [N][16] f32x2, float4 on both global sides.
__global__ __launch_bounds__(256) void transpose_out(
    const f32x4* __restrict__ ws4,
    f32x4* __restrict__ out4,
    int npoints)
{
    __shared__ f32x2 tile[NLEVELS][130];
    const int tid = threadIdx.x;
    const int base = blockIdx.x << 7;    // 128 points per block
    const int np2 = npoints >> 1;

#pragma unroll
    for (int k = 0; k < 4; ++k) {
        const int flat = tid + (k << 8);
        const int l  = flat >> 6;
        const int pr = flat & 63;
        const int gp = (base >> 1) + pr;
        if (gp < np2) {
            const f32x4 v = __builtin_nontemporal_load(ws4 + (size_t)l * np2 + gp);
            tile[l][2 * pr]     = v.xy;
            tile[l][2 * pr + 1] = v.zw;
        }
    }
    __syncthreads();

#pragma unroll
    for (int k = 0; k < 4; ++k) {
        const int flat = tid + (k << 8);
        const int nl = flat >> 3;
        const int c  = flat & 7;
        const int nn = base + nl;
        if (nn < npoints) {
            const f32x2 a = tile[2 * c][nl];
            const f32x2 b = tile[2 * c + 1][nl];
            f32x4 v; v.x = a.x; v.y = a.y; v.z = b.x; v.w = b.y;
            __builtin_nontemporal_store(v, out4 + (size_t)nn * 8 + c);
        }
    }
}

extern "C" void kernel_launch(void* const* d_in, const int* in_sizes, int n_in,
                              void* d_out, int out_size, void* d_ws, size_t ws_size,
                              hipStream_t stream) {
    const float* x     = (const float*)d_in[0];
    const float* table = (const float*)d_in[1];
    float* out         = (float*)d_out;
    const int npoints  = in_sizes[0] / 3;

    HGParams p;
    const double B = pow(2.0, 7.0 / 15.0);
    int dpk_total = 0;   // f32x4 entries for tier-B dense repack
    int dq_total = 0;    // u32x4 entries for fp16 dense quads
    int hq_total = 0;    // u32x4 entries for fp16 hashed tables
    int max_res3 = 0;
    for (int l = 0; l < NLEVELS; ++l) {
        const double s = 16.0 * pow(B, (double)l) - 1.0;
        p.scale[l] = (float)s;
        const int res = (int)ceil(s) + 1;
        p.res[l] = res;
        const long long r3 = (long long)res * res * res;
        p.dense[l] = (r3 <= (long long)HASHMAP) ? 1 : 0;
        if (p.dense[l]) {
            p.dpk_off[l] = dpk_total;  dpk_total += (int)r3;
            p.dq_off[l]  = dq_total;   dq_total  += (int)r3;
            p.hq_off[l]  = -1;
            if ((int)r3 > max_res3) max_res3 = (int)r3;
        } else {
            p.dpk_off[l] = -1;
            p.dq_off[l]  = -1;
            p.hq_off[l]  = hq_total;   hq_total  += HASHMAP / 4;
        }
    }

    const size_t need_main = (size_t)npoints * NLEVELS * sizeof(f32x2);
    const bool ws_main = (ws_size >= need_main) && ((npoints & 1) == 0);
    const size_t off0 = ws_main ? need_main : 0;

    const size_t hq_bytes = (size_t)hq_total * 16;
    const size_t dq_bytes = (size_t)dq_total * 16;
    const bool tierA = (ws_size >= off0 + hq_bytes + dq_bytes);

    const u32x4* hq = nullptr;
    const u32x4* dq = nullptr;
    const f32x4* dpk = nullptr;

    if (tierA) {
        uint32_t* hqw = (uint32_t*)((char*)d_ws + off0);
        u32x4*    dqt = (u32x4*)((char*)d_ws + off0 + hq_bytes);
        hq = (const u32x4*)hqw;
        dq = dqt;
        {
            const dim3 gr(1024, NLEVELS);
            repack_hashed_f16<<<gr, 256, 0, stream>>>(
                (const f32x4*)table, hqw, p);
        }
        {
            const dim3 gr((max_res3 + 255) / 256, NLEVELS);
            repack_dense_f16<<<gr, 256, 0, stream>>>(
                (const f32x2*)table, dqt, p);
        }
    } else {
        // tier B: fp32 dense pair repack only
        for (int l = 0; l < NLEVELS; ++l) { p.hq_off[l] = -1; p.dq_off[l] = -1; }
        const size_t need_dpk = (size_t)dpk_total * sizeof(f32x4);
        const bool use_dpk = (ws_size >= off0 + need_dpk) && dpk_total > 0;
        if (use_dpk) {
            f32x4* dpkw = (f32x4*)((char*)d_ws + off0);
            dpk = dpkw;
            const dim3 gr((max_res3 + 255) / 256, NLEVELS);
            repack_dense_k<<<gr, 256, 0, stream>>>((const f32x2*)table, dpkw, p);
        } else {
            for (int l = 0; l < NLEVELS; ++l) p.dpk_off[l] = -1;
        }
    }

    const dim3 g1((npoints + 511) / 512, NLEVELS);
    if (ws_main) {
        hashgrid_level<<<g1, 256, 0, stream>>>(
            x, table, dpk, hq, dq, (f32x2*)d_ws, p, npoints,
            (size_t)npoints, (size_t)1);
        const int nb2 = (npoints + 127) / 128;
        transpose_out<<<nb2, 256, 0, stream>>>(
            (const f32x4*)d_ws, (f32x4*)out, npoints);
    } else {
        hashgrid_level<<<g1, 256, 0, stream>>>(
            x, table, dpk, hq, dq, (f32x2*)out, p, npoints,
            (size_t)1, (size_t)NLEVELS);
    }
}

// Round 9
// 916.520 us; speedup vs baseline: 1.1124x; 1.0179x over previous
//
#include <hip/hip_runtime.h>
#include <cstdint>
#include <cmath>

// TropicalHashGrid forward, R8.
// R2: level-major dispatch -> gathers are L2-hits.
// R3: pair-packing cut lane-requests 268M -> 180M.
// R4: sc0 L1-bypass NEUTRAL.
// R5: fp16 repack: 815 -> 605us, dur proportional to gather count.
// R6: 2pt/thread @64-VGPR cap: spill-confounded.
// R7: 2pt/thread spill-free: MLP x2 NEUTRAL, store-request cut NEUTRAL.
//     MODEL LOCKED: dur ~ gather-request count only (~2.7 cyc/lane,
//     225 G req/s ~ 73% of L2-channel ceiling). Stores free. Gather kernel
//     within ~8% of its request floor.
// R8: attack the non-gather 332us: fp16 ws (transpose traffic 512->384MB,
//     main WRITE 262->131MB), u32-tile transpose, merged repack kernel.

typedef float    f32x2 __attribute__((ext_vector_type(2)));
typedef float    f32x4 __attribute__((ext_vector_type(4)));
typedef uint32_t u32x2 __attribute__((ext_vector_type(2)));
typedef uint32_t u32x4 __attribute__((ext_vector_type(4)));
typedef _Float16 h16x2 __attribute__((ext_vector_type(2)));

#define NLEVELS 16
#define HASHMAP (1 << 19)
#define HMASK ((uint32_t)(HASHMAP - 1))
#define PRIME_Y 2654435761u
#define PRIME_Z 805459861u
#define F16SCALE 1024.0f
#define F16UNSCALE (1.0f / 1024.0f)

struct HGParams {
    float scale[NLEVELS];
    int   res[NLEVELS];
    int   dense[NLEVELS];
    int   dpk_off[NLEVELS];  // tier-B fp32 dense pair repack, f32x4 units, -1 none
    int   hq_off[NLEVELS];   // fp16 hashed table, u32x4 units, -1 none
    int   dq_off[NLEVELS];   // fp16 dense 2x2 quad table, u32x4 units, -1 none
};

__device__ __forceinline__ uint32_t sel4(u32x4 q, uint32_t k) {
    const uint32_t a = (k & 1u) ? q.y : q.x;
    const uint32_t b = (k & 1u) ? q.w : q.z;
    return (k & 2u) ? b : a;
}
__device__ __forceinline__ void unpack_h2(uint32_t w, float& lo, float& hi) {
    const h16x2 h = __builtin_bit_cast(h16x2, w);
    lo = (float)h.x; hi = (float)h.y;
}
__device__ __forceinline__ uint32_t pack_h2(float a, float b) {
    h16x2 h; h.x = (_Float16)a; h.y = (_Float16)b;
    return __builtin_bit_cast(uint32_t, h);
}

// ---- merged fp16 repack: hashed identity-layout + dense 2x2 xy-quads ----
__global__ __launch_bounds__(256) void repack_all_f16(
    const float* __restrict__ table, uint32_t* __restrict__ hqw,
    u32x4* __restrict__ dqt, HGParams p)
{
    const int l = blockIdx.y;
    if (p.dense[l]) {
        if (p.dq_off[l] < 0) return;
        const int res = p.res[l];
        const int rm = res - 1;
        const int r2 = res * res;
        const int res3 = r2 * res;
        const f32x2* __restrict__ src =
            (const f32x2*)table + (size_t)l * HASHMAP;
        u32x4* __restrict__ dst = dqt + p.dq_off[l];
        for (int k = blockIdx.x * 256 + threadIdx.x; k < res3;
             k += gridDim.x * 256) {
            const int x = k % res;
            const int t = k / res;
            const int y = t % res;
            const int dx = (x < rm) ? 1 : 0;
            const int dy = (y < rm) ? res : 0;
            const f32x2 e00 = src[k];
            const f32x2 e10 = src[k + dx];
            const f32x2 e01 = src[k + dy];
            const f32x2 e11 = src[k + dx + dy];
            u32x4 w;
            w.x = pack_h2(e00.x * F16SCALE, e00.y * F16SCALE);
            w.y = pack_h2(e10.x * F16SCALE, e10.y * F16SCALE);
            w.z = pack_h2(e01.x * F16SCALE, e01.y * F16SCALE);
            w.w = pack_h2(e11.x * F16SCALE, e11.y * F16SCALE);
            dst[k] = w;
        }
    } else {
        if (p.hq_off[l] < 0) return;
        const f32x4* __restrict__ src =
            (const f32x4*)table + (size_t)l * (HASHMAP / 2);
        u32x2* __restrict__ dst = (u32x2*)(hqw + (size_t)p.hq_off[l] * 4);
        for (int k = blockIdx.x * 256 + threadIdx.x; k < HASHMAP / 2;
             k += gridDim.x * 256) {
            const f32x4 v = src[k];   // two entries
            u32x2 w;
            w.x = pack_h2(v.x * F16SCALE, v.y * F16SCALE);
            w.y = pack_h2(v.z * F16SCALE, v.w * F16SCALE);
            dst[k] = w;
        }
    }
}

// ---- tier-B fp32 dense pair repack (fallback) ----
__global__ __launch_bounds__(256) void repack_dense_k(
    const f32x2* __restrict__ table, f32x4* __restrict__ dpk, HGParams p)
{
    const int l = blockIdx.y;
    if (!p.dense[l] || p.dpk_off[l] < 0) return;
    const int res = p.res[l];
    const int res3 = res * res * res;
    const f32x2* __restrict__ src = table + (size_t)l * HASHMAP;
    f32x4* __restrict__ dst = dpk + p.dpk_off[l];
    for (int k = blockIdx.x * 256 + threadIdx.x; k < res3; k += gridDim.x * 256) {
        const f32x2 a = src[k];
        const f32x2 b = src[k + 1];
        f32x4 v; v.x = a.x; v.y = a.y; v.z = b.x; v.w = b.y;
        dst[k] = v;
    }
}

// Tier-B fp32 per-point fallback (dead in practice when tier-A ws fits).
// Returns SCALED (x1024) outputs to match tier-A domain.
__device__ __forceinline__ void point_fp32(
    const f32x2* __restrict__ tbl, const f32x4* __restrict__ dpkt,
    bool dense, int res,
    float rx, float ry, float rz, int ix, int iy, int iz,
    float& ox, float& oy)
{
    const float wx0 = 1.0f - rx, wx1 = rx;
    const float wy_[2] = {1.0f - ry, ry};
    const float wz_[2] = {1.0f - rz, rz};
    float ax = 0.0f, ay = 0.0f;
    if (dense) {
        const int rm = res - 1;
        const int x0 = min(ix, rm), x1 = min(ix + 1, rm);
        const int y0 = min(iy, rm), y1 = min(iy + 1, rm);
        const int z0 = min(iz, rm), z1 = min(iz + 1, rm);
        const int r2 = res * res;
        const int ys[2] = {y0 * res, y1 * res};
        const int zs[2] = {z0 * r2,  z1 * r2};
        const int d = x1 - x0;
        if (dpkt) {
            f32x4 f4[4];
#pragma unroll
            for (int c = 0; c < 4; ++c)
                f4[c] = dpkt[x0 + ys[(c >> 1) & 1] + zs[c & 1]];
#pragma unroll
            for (int c = 0; c < 4; ++c) {
                const f32x2 c0 = f4[c].xy;
                const f32x2 c1 = d ? f4[c].zw : f4[c].xy;
                const float wyz = wy_[(c >> 1) & 1] * wz_[c & 1];
                ax += wyz * (wx0 * c0.x + wx1 * c1.x);
                ay += wyz * (wx0 * c0.y + wx1 * c1.y);
            }
        } else {
            f32x2 f0[4], f1[4];
#pragma unroll
            for (int c = 0; c < 4; ++c) {
                const int b = ys[(c >> 1) & 1] + zs[c & 1];
                f0[c] = tbl[x0 + b];
                f1[c] = tbl[x1 + b];
            }
#pragma unroll
            for (int c = 0; c < 4; ++c) {
                const float wyz = wy_[(c >> 1) & 1] * wz_[c & 1];
                ax += wyz * (wx0 * f0[c].x + wx1 * f1[c].x);
                ay += wyz * (wx0 * f0[c].y + wx1 * f1[c].y);
            }
        }
    } else {
        const uint32_t ux = (uint32_t)ix;
        const uint32_t hy[2] = {(uint32_t)iy * PRIME_Y, (uint32_t)(iy + 1) * PRIME_Y};
        const uint32_t hz[2] = {(uint32_t)iz * PRIME_Z, (uint32_t)(iz + 1) * PRIME_Z};
        uint32_t H0[4], H1[4];
#pragma unroll
        for (int c = 0; c < 4; ++c) {
            const uint32_t hyz = hy[(c >> 1) & 1] ^ hz[c & 1];
            H0[c] = (ux ^ hyz) & HMASK;
            H1[c] = ((ux + 1u) ^ hyz) & HMASK;
        }
        const f32x4* __restrict__ t4 = (const f32x4*)tbl;
        f32x4 f4[4];
#pragma unroll
        for (int c = 0; c < 4; ++c) f4[c] = t4[H0[c] >> 1];
        f32x2 c1v[4];
        if (ux & 1u) {
#pragma unroll
            for (int c = 0; c < 4; ++c) c1v[c] = tbl[H1[c]];
        } else {
#pragma unroll
            for (int c = 0; c < 4; ++c)
                c1v[c] = (H0[c] & 1u) ? f4[c].xy : f4[c].zw;
        }
#pragma unroll
        for (int c = 0; c < 4; ++c) {
            const f32x2 c0 = (H0[c] & 1u) ? f4[c].zw : f4[c].xy;
            const float wyz = wy_[(c >> 1) & 1] * wz_[c & 1];
            ax += wyz * (wx0 * c0.x + wx1 * c1v[c].x);
            ay += wyz * (wx0 * c0.y + wx1 * c1v[c].y);
        }
    }
    ox = ax * F16SCALE; oy = ay * F16SCALE;  // scaled domain
}

// One block = 512 points x 1 level (2 points/thread; neutral but enables the
// paired stores). Level = blockIdx.y (slowest -> one table hot per XCD L2).
// Outputs kept in x1024-scaled domain; ws path stores packed fp16, direct
// path unscales to fp32.
__global__ __launch_bounds__(256) void hashgrid_level(
    const float* __restrict__ x,
    const float* __restrict__ table,
    const f32x4* __restrict__ dpk,   // tier-B fp32 dense pairs or nullptr
    const u32x4* __restrict__ hq,    // fp16 hashed tables or nullptr
    const u32x4* __restrict__ dq,    // fp16 dense quads or nullptr
    f32x2* __restrict__ dst32,       // direct fp32 out [N][16] or nullptr
    uint32_t* __restrict__ dsth,     // fp16 ws [16][N] or nullptr
    HGParams p,
    int npoints)
{
    __shared__ float sx[1536];
    const int tid = threadIdx.x;
    const int base = blockIdx.x << 9;   // 512 points/block
    const int l = blockIdx.y;

    const int total = npoints * 3;
    const int sbase = base * 3;
#pragma unroll
    for (int k = 0; k < 6; ++k) {
        const int li = tid + (k << 8);
        const int gi = sbase + li;
        sx[li] = (gi < total) ? x[gi] : 0.0f;
    }
    __syncthreads();

    const int n0 = base + (tid << 1);
    if (n0 >= npoints) return;
    const bool pair = (n0 + 1) < npoints;

    const float scale = p.scale[l];
    const int   res   = p.res[l];
    const bool  dense = (p.dense[l] != 0);

    float rx[2], ry[2], rz[2];
    int ixv[2], iyv[2], izv[2];
#pragma unroll
    for (int j = 0; j < 2; ++j) {
        const int s = ((tid << 1) | j) * 3;
        const float px = sx[s + 0] * scale + 0.5f;
        const float py = sx[s + 1] * scale + 0.5f;
        const float pz = sx[s + 2] * scale + 0.5f;
        const float fx = floorf(px), fy = floorf(py), fz = floorf(pz);
        rx[j] = px - fx; ry[j] = py - fy; rz[j] = pz - fz;
        ixv[j] = (int)fx; iyv[j] = (int)fy; izv[j] = (int)fz;
    }

    float ox[2], oy[2];   // x1024-scaled outputs

    if (dense && dq && p.dq_off[l] >= 0) {
        // fp16 2x2 xy-quads: one 16B request per z-corner, 2 pts interleaved.
        const u32x4* __restrict__ dt = dq + p.dq_off[l];
        const int rm = res - 1, r2 = res * res;
        u32x4 qa[2], qb[2];
#pragma unroll
        for (int j = 0; j < 2; ++j) {
            const int x0 = min(ixv[j], rm), y0 = min(iyv[j], rm);
            const int z0 = min(izv[j], rm), z1 = min(izv[j] + 1, rm);
            const int b = x0 + y0 * res;
            qa[j] = dt[b + z0 * r2];
            qb[j] = dt[b + z1 * r2];
        }
#pragma unroll
        for (int j = 0; j < 2; ++j) {
            const float wx0 = 1.0f - rx[j], wx1 = rx[j];
            const float wy0 = 1.0f - ry[j], wy1 = ry[j];
            const float wz0 = 1.0f - rz[j], wz1 = rz[j];
            float a00x, a00y, a10x, a10y, a01x, a01y, a11x, a11y;
            unpack_h2(qa[j].x, a00x, a00y);
            unpack_h2(qa[j].y, a10x, a10y);
            unpack_h2(qa[j].z, a01x, a01y);
            unpack_h2(qa[j].w, a11x, a11y);
            const float bax = wy0 * (wx0 * a00x + wx1 * a10x)
                            + wy1 * (wx0 * a01x + wx1 * a11x);
            const float bay = wy0 * (wx0 * a00y + wx1 * a10y)
                            + wy1 * (wx0 * a01y + wx1 * a11y);
            float b00x, b00y, b10x, b10y, b01x, b01y, b11x, b11y;
            unpack_h2(qb[j].x, b00x, b00y);
            unpack_h2(qb[j].y, b10x, b10y);
            unpack_h2(qb[j].z, b01x, b01y);
            unpack_h2(qb[j].w, b11x, b11y);
            const float bbx = wy0 * (wx0 * b00x + wx1 * b10x)
                            + wy1 * (wx0 * b01x + wx1 * b11x);
            const float bby = wy0 * (wx0 * b00y + wx1 * b10y)
                            + wy1 * (wx0 * b01y + wx1 * b11y);
            ox[j] = wz0 * bax + wz1 * bbx;
            oy[j] = wz0 * bay + wz1 * bby;
        }
    } else if (!dense && hq && p.hq_off[l] >= 0) {
        // fp16 hashed quads, 2 points: 8 quad loads + masked straddle dwords.
        const u32x4* __restrict__ ht = hq + p.hq_off[l];
        const uint32_t* __restrict__ htw = (const uint32_t*)ht;
        uint32_t H0[2][4], dxm[2];
#pragma unroll
        for (int j = 0; j < 2; ++j) {
            const uint32_t ux = (uint32_t)ixv[j];
            const uint32_t hy0 = (uint32_t)iyv[j] * PRIME_Y;
            const uint32_t hy1 = (uint32_t)(iyv[j] + 1) * PRIME_Y;
            const uint32_t hz0 = (uint32_t)izv[j] * PRIME_Z;
            const uint32_t hz1 = (uint32_t)(izv[j] + 1) * PRIME_Z;
#pragma unroll
            for (int c = 0; c < 4; ++c) {
                const uint32_t hyz = ((c & 2) ? hy1 : hy0) ^ ((c & 1) ? hz1 : hz0);
                H0[j][c] = (ux ^ hyz) & HMASK;
            }
            dxm[j] = (ux ^ (ux + 1u)) & HMASK;  // H1 = H0 ^ dxm
        }
        u32x4 q0[2][4];
#pragma unroll
        for (int j = 0; j < 2; ++j)
#pragma unroll
            for (int c = 0; c < 4; ++c)
                q0[j][c] = ht[H0[j][c] >> 2];
        uint32_t sE[2][4];
#pragma unroll
        for (int j = 0; j < 2; ++j) {
            if (dxm[j] >= 4u) {                 // quad-straddle iff ix%4==3
#pragma unroll
                for (int c = 0; c < 4; ++c)
                    sE[j][c] = htw[H0[j][c] ^ dxm[j]];  // single-dword fetch
            }
        }
#pragma unroll
        for (int j = 0; j < 2; ++j) {
            const float wx0 = 1.0f - rx[j], wx1 = rx[j];
            const float wy0 = 1.0f - ry[j], wy1 = ry[j];
            const float wz0 = 1.0f - rz[j], wz1 = rz[j];
            const bool st = (dxm[j] >= 4u);
            float ax = 0.0f, ay = 0.0f;
#pragma unroll
            for (int c = 0; c < 4; ++c) {
                const uint32_t k0 = H0[j][c] & 3u;
                const uint32_t e0 = sel4(q0[j][c], k0);
                const uint32_t e1 = st ? sE[j][c]
                                       : sel4(q0[j][c], k0 ^ (dxm[j] & 3u));
                float c0x, c0y, c1x, c1y;
                unpack_h2(e0, c0x, c0y);
                unpack_h2(e1, c1x, c1y);
                const float wyz = ((c & 2) ? wy1 : wy0) * ((c & 1) ? wz1 : wz0);
                ax += wyz * (wx0 * c0x + wx1 * c1x);
                ay += wyz * (wx0 * c0y + wx1 * c1y);
            }
            ox[j] = ax;
            oy[j] = ay;
        }
    } else {
        // tier-B fp32 fallback, sequential per point (outputs scaled).
        const f32x2* __restrict__ tbl =
            (const f32x2*)table + (size_t)l * (size_t)HASHMAP;
        const f32x4* __restrict__ dpkt =
            (dense && dpk && p.dpk_off[l] >= 0) ? (dpk + p.dpk_off[l]) : nullptr;
#pragma unroll
        for (int j = 0; j < 2; ++j)
            point_fp32(tbl, dpkt, dense, res,
                       rx[j], ry[j], rz[j], ixv[j], iyv[j], izv[j],
                       ox[j], oy[j]);
    }

    if (dsth) {
        // ws path: npoints even, n0 even -> pair always valid, 8B aligned.
        u32x2 w;
        w.x = pack_h2(ox[0], oy[0]);
        w.y = pack_h2(ox[1], oy[1]);
        __builtin_nontemporal_store(
            w, (u32x2*)(dsth + (size_t)l * npoints + n0));
    } else {
        // direct fp32 out [N][16] f32x2
        f32x2 a; a.x = ox[0] * F16UNSCALE; a.y = oy[0] * F16UNSCALE;
        __builtin_nontemporal_store(a, dst32 + (size_t)n0 * NLEVELS + l);
        if (pair) {
            f32x2 b2; b2.x = ox[1] * F16UNSCALE; b2.y = oy[1] * F16UNSCALE;
            __builtin_nontemporal_store(b2, dst32 + (size_t)(n0 + 1) * NLEVELS + l);
        }
    }
}

// Transpose fp16 ws [16][N] u32 -> out [N][16] f32x2, with unscale.
// Block = 256 points. Requires npoints % 4 == 0 (guarded at launch).
__global__ __launch_bounds__(256) void transpose_out_f16(
    const u32x4* __restrict__ ws4,
    f32x4* __restrict__ out4,
    int npoints)
{
    __shared__ uint32_t tile[NLEVELS][260];  // pad staggers banks
    const int tid = threadIdx.x;
    const int base = blockIdx.x << 8;    // 256 points per block
    const int np4 = npoints >> 2;        // ws row length in u32x4

    // Load: each wave covers one level (f>>6 wave-uniform), 64 u32x4 = 1 KiB.
#pragma unroll
    for (int k = 0; k < 4; ++k) {
        const int f = tid + (k << 8);
        const int lv = f >> 6;           // 0..15
        const int p4 = f & 63;           // u32x4 group within tile
        const int gp = (base >> 2) + p4;
        if (gp < np4) {
            const u32x4 v = __builtin_nontemporal_load(ws4 + (size_t)lv * np4 + gp);
            tile[lv][4 * p4 + 0] = v.x;
            tile[lv][4 * p4 + 1] = v.y;
            tile[lv][4 * p4 + 2] = v.z;
            tile[lv][4 * p4 + 3] = v.w;
        }
    }
    __syncthreads();

    // Store: out row per point = 8 f32x4, fully coalesced; unpack + unscale.
#pragma unroll
    for (int k = 0; k < 8; ++k) {
        const int f = tid + (k << 8);
        const int pl = f >> 3;           // local point 0..255
        const int c  = f & 7;            // level pair 0..7
        const int nn = base + pl;
        if (nn < npoints) {
            float ax, ay, bx, by;
            unpack_h2(tile[2 * c][pl],     ax, ay);
            unpack_h2(tile[2 * c + 1][pl], bx, by);
            f32x4 v;
            v.x = ax * F16UNSCALE; v.y = ay * F16UNSCALE;
            v.z = bx * F16UNSCALE; v.w = by * F16UNSCALE;
            __builtin_nontemporal_store(v, out4 + (size_t)nn * 8 + c);
        }
    }
}

extern "C" void kernel_launch(void* const* d_in, const int* in_sizes, int n_in,
                              void* d_out, int out_size, void* d_ws, size_t ws_size,
                              hipStream_t stream) {
    const float* x     = (const float*)d_in[0];
    const float* table = (const float*)d_in[1];
    float* out         = (float*)d_out;
    const int npoints  = in_sizes[0] / 3;

    HGParams p;
    const double B = pow(2.0, 7.0 / 15.0);
    int dpk_total = 0;   // f32x4 entries for tier-B dense repack
    int dq_total = 0;    // u32x4 entries for fp16 dense quads
    int hq_total = 0;    // u32x4 entries for fp16 hashed tables
    int max_res3 = 0;
    for (int l = 0; l < NLEVELS; ++l) {
        const double s = 16.0 * pow(B, (double)l) - 1.0;
        p.scale[l] = (float)s;
        const int res = (int)ceil(s) + 1;
        p.res[l] = res;
        const long long r3 = (long long)res * res * res;
        p.dense[l] = (r3 <= (long long)HASHMAP) ? 1 : 0;
        if (p.dense[l]) {
            p.dpk_off[l] = dpk_total;  dpk_total += (int)r3;
            p.dq_off[l]  = dq_total;   dq_total  += (int)r3;
            p.hq_off[l]  = -1;
            if ((int)r3 > max_res3) max_res3 = (int)r3;
        } else {
            p.dpk_off[l] = -1;
            p.dq_off[l]  = -1;
            p.hq_off[l]  = hq_total;   hq_total  += HASHMAP / 4;
        }
    }

    // fp16 ws: [16][N] u32. Transpose needs npoints % 4 == 0.
    const size_t need_main = (size_t)npoints * NLEVELS * sizeof(uint32_t);
    const bool ws_main = (ws_size >= need_main) && ((npoints & 3) == 0);
    const size_t off0 = ws_main ? need_main : 0;

    const size_t hq_bytes = (size_t)hq_total * 16;
    const size_t dq_bytes = (size_t)dq_total * 16;
    const bool tierA = (ws_size >= off0 + hq_bytes + dq_bytes);

    const u32x4* hq = nullptr;
    const u32x4* dq = nullptr;
    const f32x4* dpk = nullptr;

    if (tierA) {
        uint32_t* hqw = (uint32_t*)((char*)d_ws + off0);
        u32x4*    dqt = (u32x4*)((char*)d_ws + off0 + hq_bytes);
        hq = (const u32x4*)hqw;
        dq = dqt;
        const int gx_h = (HASHMAP / 2 + 255) / 256;        // 1024
        const int gx_d = (max_res3 + 255) / 256;
        const int gx = gx_h > gx_d ? gx_h : gx_d;
        const dim3 gr(gx, NLEVELS);
        repack_all_f16<<<gr, 256, 0, stream>>>(table, hqw, dqt, p);
    } else {
        // tier B: fp32 dense pair repack only
        for (int l = 0; l < NLEVELS; ++l) { p.hq_off[l] = -1; p.dq_off[l] = -1; }
        const size_t need_dpk = (size_t)dpk_total * sizeof(f32x4);
        const bool use_dpk = (ws_size >= off0 + need_dpk) && dpk_total > 0;
        if (use_dpk) {
            f32x4* dpkw = (f32x4*)((char*)d_ws + off0);
            dpk = dpkw;
            const dim3 gr((max_res3 + 255) / 256, NLEVELS);
            repack_dense_k<<<gr, 256, 0, stream>>>((const f32x2*)table, dpkw, p);
        } else {
            for (int l = 0; l < NLEVELS; ++l) p.dpk_off[l] = -1;
        }
    }

    const dim3 g1((npoints + 511) / 512, NLEVELS);
    if (ws_main) {
        hashgrid_level<<<g1, 256, 0, stream>>>(
            x, table, dpk, hq, dq, nullptr, (uint32_t*)d_ws, p, npoints);
        const int nb2 = (npoints + 255) / 256;
        transpose_out_f16<<<nb2, 256, 0, stream>>>(
            (const u32x4*)d_ws, (f32x4*)out, npoints);
    } else {
        hashgrid_level<<<g1, 256, 0, stream>>>(
            x, table, dpk, hq, dq, (f32x2*)out, nullptr, p, npoints);
    }
}